// Round 17
// baseline (43.360 us; speedup 1.0000x reference)
//
#include <hip/hip_runtime.h>
#include <hip/hip_bf16.h>

#define OUT_N 8192
#define IN_K  8192
#define M_ROWS 64

typedef __attribute__((ext_vector_type(8))) short  bf16x8;
typedef __attribute__((ext_vector_type(4))) float  f32x4;
typedef __attribute__((ext_vector_type(2))) float  f32x2;
typedef __attribute__((ext_vector_type(4))) int    int4v;

__device__ const float NF4_TAB[16] = {
  -1.0f, -0.6961928009986877f, -0.5250730514526367f, -0.39491748809814453f,
  -0.28444138169288635f, -0.18477343022823334f, -0.09105003625154495f, 0.0f,
  0.07958029955625534f, 0.16093020141124725f, 0.24611230850219726f,
  0.33791524171829224f, 0.44070982933044434f, 0.5626170039176941f,
  0.7229568362236023f, 1.0f };

static __device__ __forceinline__ unsigned short f2bf(float f) {
  union { __hip_bfloat16 h; unsigned short s; } u;
  u.h = __float2bfloat16(f);
  return u.s;
}

static __device__ __forceinline__ void gload_lds16(const void* g, void* s) {
  __builtin_amdgcn_global_load_lds((const __attribute__((address_space(1))) void*)g,
                                   (__attribute__((address_space(3))) void*)s,
                                   16, 0, 0);
}

// Repack x (fp32 [64][8192]) -> bf16 MFMA A-fragment order.
// xf[((ks*4 + mt)*64 + lane)*8 + j] = bf16(x[mt*16+(lane&15)][ks*32+(lane>>4)*8+j])
__global__ __launch_bounds__(256) void qlin_prep(const float* __restrict__ x,
                                                 unsigned short* __restrict__ xf) {
  int t = blockIdx.x * 256 + threadIdx.x;          // (ks, mt, lane)
  int lane = t & 63, mt = (t >> 6) & 3, ks = t >> 8;
  int ri = lane & 15, kbb = lane >> 4;
  const float* src = x + (size_t)(mt * 16 + ri) * IN_K + ks * 32 + kbb * 8;
  f32x4 a = *(const f32x4*)src;
  f32x4 c = *(const f32x4*)(src + 4);
  bf16x8 o;
  o[0] = (short)f2bf(a[0]); o[1] = (short)f2bf(a[1]);
  o[2] = (short)f2bf(a[2]); o[3] = (short)f2bf(a[3]);
  o[4] = (short)f2bf(c[0]); o[5] = (short)f2bf(c[1]);
  o[6] = (short)f2bf(c[2]); o[7] = (short)f2bf(c[3]);
  ((bf16x8*)xf)[t] = o;
}

// dequant 4 packed code-bytes + fold absmax in f32 (R13-proven numerics):
// 4 pair-LUT reads -> unpack -> *am -> bf16 (compiler uses cvt_pk)
static __device__ __forceinline__ bf16x8 deqscale(const unsigned int* lut,
                                                  unsigned b, float am) {
  unsigned p0 = lut[b & 255];
  unsigned p1 = lut[(b >> 8) & 255];
  unsigned p2 = lut[(b >> 16) & 255];
  unsigned p3 = lut[b >> 24];
  bf16x8 r;
  r[0] = (short)f2bf(__uint_as_float(p0 << 16) * am);
  r[1] = (short)f2bf(__uint_as_float(p0 & 0xffff0000u) * am);
  r[2] = (short)f2bf(__uint_as_float(p1 << 16) * am);
  r[3] = (short)f2bf(__uint_as_float(p1 & 0xffff0000u) * am);
  r[4] = (short)f2bf(__uint_as_float(p2 << 16) * am);
  r[5] = (short)f2bf(__uint_as_float(p2 & 0xffff0000u) * am);
  r[6] = (short)f2bf(__uint_as_float(p3 << 16) * am);
  r[7] = (short)f2bf(__uint_as_float(p3 & 0xffff0000u) * am);
  return r;
}

// Shared-memory overlay: main-loop state vs epilogue bf16 transpose tile.
union SMem {
  struct {
    unsigned int lut[256];        // byte -> {bf16(nf4[lo]), bf16(nf4[hi])}
    bf16x8 ast[2][4][256];        // [buf][kstep-in-phase][mt*64+lane]  32 KB
  } s;
  unsigned short tlb[64][136];    // 64 rows x 128 cols bf16, stride 136 (17 KB)
};

// wave w stages k-step (4*PH + w) of the chunk into typed LDS buffer BUF.
#define STAGE(BUF, PH) {                                                      \
    const char* _s = xfb + (((size_t)(PH) * 4 + w) * 4096) + l * 16;          \
    gload_lds16(_s,        &ast[BUF][w][0]);                                  \
    gload_lds16(_s + 1024, &ast[BUF][w][64]);                                 \
    gload_lds16(_s + 2048, &ast[BUF][w][128]);                                \
    gload_lds16(_s + 3072, &ast[BUF][w][192]); }

// one k-step, TWO column groups sharing the same 4 A-fragments:
// 2 pk refills (+2 ksteps ahead), 2 packed ds_bpermute, 2 dequant+scale,
// 8 MFMA accumulating directly into mn0..7.
#define CSTEP(S, PKA, PKB, AMA, AMB) {                                        \
    int _nk = KS + (S) + 2; if (_nk > NITm1) _nk = NITm1;                     \
    bf16x8 A0 = ast[cur][S][l];                                               \
    bf16x8 A1 = ast[cur][S][64 + l];                                          \
    bf16x8 A2 = ast[cur][S][128 + l];                                         \
    bf16x8 A3 = ast[cur][S][192 + l];                                         \
    int4v _na = *(const int4v*)(pcoalA + (size_t)_nk * 64);                   \
    int4v _nb = *(const int4v*)(pcoalB + (size_t)_nk * 64);                   \
    unsigned _pa = (unsigned)PKA[0] | ((unsigned)PKA[1] << 8)                 \
                 | ((unsigned)PKA[2] << 16) | ((unsigned)PKA[3] << 24);       \
    unsigned _pb = (unsigned)PKB[0] | ((unsigned)PKB[1] << 8)                 \
                 | ((unsigned)PKB[2] << 16) | ((unsigned)PKB[3] << 24);       \
    unsigned _ba = (unsigned)__builtin_amdgcn_ds_bpermute(bpidx, (int)_pa);   \
    unsigned _bb = (unsigned)__builtin_amdgcn_ds_bpermute(bpidx, (int)_pb);   \
    bf16x8 bA = deqscale(lut, _ba, AMA);                                      \
    bf16x8 bB = deqscale(lut, _bb, AMB);                                      \
    mn0 = __builtin_amdgcn_mfma_f32_16x16x32_bf16(A0, bA, mn0, 0, 0, 0);      \
    mn1 = __builtin_amdgcn_mfma_f32_16x16x32_bf16(A1, bA, mn1, 0, 0, 0);      \
    mn2 = __builtin_amdgcn_mfma_f32_16x16x32_bf16(A2, bA, mn2, 0, 0, 0);      \
    mn3 = __builtin_amdgcn_mfma_f32_16x16x32_bf16(A3, bA, mn3, 0, 0, 0);      \
    mn4 = __builtin_amdgcn_mfma_f32_16x16x32_bf16(A0, bB, mn4, 0, 0, 0);      \
    mn5 = __builtin_amdgcn_mfma_f32_16x16x32_bf16(A1, bB, mn5, 0, 0, 0);      \
    mn6 = __builtin_amdgcn_mfma_f32_16x16x32_bf16(A2, bB, mn6, 0, 0, 0);      \
    mn7 = __builtin_amdgcn_mfma_f32_16x16x32_bf16(A3, bB, mn7, 0, 0, 0);      \
    PKA = _na; PKB = _nb; }

// Fused NF4 dequant + GEMM, 128-col blocks: each wave computes 32 cols (two
// B-fragments) sharing the SAME A-fragments -> A-LDS work per output halves.
// pk: coalesced 16-sector loads + packed ds_bpermute, 2-slot NAMED ring per
// group. A: typed-LDS double-buffered staging (4 k-steps/phase), counted
// vmcnt(4). absmax folded in f32 during dequant (no sb registers).
template<int NC>
__global__ __launch_bounds__(256, 2) void qlin_main(
    const int*   __restrict__ packed,
    const float* __restrict__ absmax,
    const unsigned short* __restrict__ xf,
    unsigned short* __restrict__ parts) {
  constexpr int KCn   = IN_K / NC;     // k per chunk (512 for NC=16)
  constexpr int NIT   = KCn / 32;      // k-steps per chunk (16 for NC=16)
  constexpr int NITm1 = NIT - 1;
  constexpr int NPH   = NIT / 4;       // phases
  constexpr int LOG   = (NC == 16) ? 4 : 3;

  __shared__ SMem sm;
  auto& ast = sm.s.ast;
  {
    int t = threadIdx.x;
    unsigned lo = f2bf(NF4_TAB[t & 15]);
    unsigned hi = f2bf(NF4_TAB[(t >> 4) & 15]);
    sm.s.lut[t] = lo | (hi << 16);
  }
  __syncthreads();
  const unsigned int* lut = &sm.s.lut[0];

  const int l     = threadIdx.x & 63;
  const int w     = threadIdx.x >> 6;
  const int ntile = (int)blockIdx.x >> LOG;        // 0..63 (128-col tiles)
  const int chunk = (int)blockIdx.x & (NC - 1);
  const int c0    = ntile * 128 + w * 32;          // wave's first col
  const int colA  = c0 + (l & 15);
  const int kb    = l >> 4;
  const int kc0   = chunk * KCn;
  const int ksg0  = kc0 >> 5;

  // coalesced pk: lane l reads 16B piece (l&3) of col c0+(l>>2); kstep stride 64B
  const char* pcoalA = (const char*)packed
                     + ((size_t)(c0 + (l >> 2)) * (IN_K / 2) + kc0 / 2) * 4
                     + (l & 3) * 16;
  const char* pcoalB = pcoalA + (size_t)16 * (IN_K / 2) * 4;
  // dest lane (c=l&15, q=l>>4) pulls from src lane 4c+q (byte index)
  const int bpidx = (((l & 15) << 2) | (l >> 4)) << 2;

  const char* xfb = (const char*)xf + (size_t)ksg0 * 4096;   // chunk xf base
  const f32x2* aptrA = (const f32x2*)(absmax + (size_t)colA * 128 + (kc0 >> 6));
  const f32x2* aptrB = (const f32x2*)(absmax + (size_t)(colA + 16) * 128 + (kc0 >> 6));

  const f32x4 zro = {0.f, 0.f, 0.f, 0.f};
  f32x4 mn0 = zro, mn1 = zro, mn2 = zro, mn3 = zro;
  f32x4 mn4 = zro, mn5 = zro, mn6 = zro, mn7 = zro;
  int4v pkA0, pkA1, pkB0, pkB1;

  // ---- prologue: absmax(2) -> stage phase0(4) -> [pin] -> pk ring(4)
  f32x2 amA = aptrA[0], amB = aptrB[0];
  STAGE(0, 0);
  __builtin_amdgcn_sched_barrier(0);
  pkA0 = *(const int4v*)(pcoalA);
  pkA1 = *(const int4v*)(pcoalA + 64);
  pkB0 = *(const int4v*)(pcoalB);
  pkB1 = *(const int4v*)(pcoalB + 64);
  asm volatile("s_waitcnt vmcnt(4)" ::: "memory");   // stages+absmax retired
  __builtin_amdgcn_s_barrier();

  for (int ph = 0; ph < NPH; ++ph) {
    const int KS  = ph * 4;
    const int cur = ph & 1;

    int pn = ph + 1; if (pn > NPH - 1) pn = NPH - 1;
    f32x2 pmA = aptrA[pn], pmB = aptrB[pn];
    if (ph + 1 < NPH) STAGE(cur ^ 1, ph + 1);
    __builtin_amdgcn_sched_barrier(0);   // pin {absmax,stage} before cstep loads

    CSTEP(0, pkA0, pkB0, amA[0], amB[0])
    CSTEP(1, pkA1, pkB1, amA[0], amB[0])
    CSTEP(2, pkA0, pkB0, amA[1], amB[1])
    CSTEP(3, pkA1, pkB1, amA[1], amB[1])

    amA = pmA; amB = pmB;
    // vmcnt(4): only the last 2 ksteps' 4 pk refills may stay outstanding;
    // stages+absmax (older, pinned) provably retired -> buf^1 ready.
    asm volatile("s_waitcnt vmcnt(4)" ::: "memory");
    asm volatile("s_waitcnt lgkmcnt(0)" ::: "memory"); // my reads of buf done
    __builtin_amdgcn_s_barrier();
  }

  // ---- epilogue: bf16-pack + transpose through overlaid LDS tile, then
  // fully-contiguous tile-major stores (256B/row, 16 threads/row).
  {
    const int ca = w * 32 + (l & 15);       // block-local colA
    const int r0 = kb * 4;
    sm.tlb[0  + r0 + 0][ca] = f2bf(mn0[0]);
    sm.tlb[0  + r0 + 1][ca] = f2bf(mn0[1]);
    sm.tlb[0  + r0 + 2][ca] = f2bf(mn0[2]);
    sm.tlb[0  + r0 + 3][ca] = f2bf(mn0[3]);
    sm.tlb[16 + r0 + 0][ca] = f2bf(mn1[0]);
    sm.tlb[16 + r0 + 1][ca] = f2bf(mn1[1]);
    sm.tlb[16 + r0 + 2][ca] = f2bf(mn1[2]);
    sm.tlb[16 + r0 + 3][ca] = f2bf(mn1[3]);
    sm.tlb[32 + r0 + 0][ca] = f2bf(mn2[0]);
    sm.tlb[32 + r0 + 1][ca] = f2bf(mn2[1]);
    sm.tlb[32 + r0 + 2][ca] = f2bf(mn2[2]);
    sm.tlb[32 + r0 + 3][ca] = f2bf(mn2[3]);
    sm.tlb[48 + r0 + 0][ca] = f2bf(mn3[0]);
    sm.tlb[48 + r0 + 1][ca] = f2bf(mn3[1]);
    sm.tlb[48 + r0 + 2][ca] = f2bf(mn3[2]);
    sm.tlb[48 + r0 + 3][ca] = f2bf(mn3[3]);
    const int cb = ca + 16;                 // block-local colB
    sm.tlb[0  + r0 + 0][cb] = f2bf(mn4[0]);
    sm.tlb[0  + r0 + 1][cb] = f2bf(mn4[1]);
    sm.tlb[0  + r0 + 2][cb] = f2bf(mn4[2]);
    sm.tlb[0  + r0 + 3][cb] = f2bf(mn4[3]);
    sm.tlb[16 + r0 + 0][cb] = f2bf(mn5[0]);
    sm.tlb[16 + r0 + 1][cb] = f2bf(mn5[1]);
    sm.tlb[16 + r0 + 2][cb] = f2bf(mn5[2]);
    sm.tlb[16 + r0 + 3][cb] = f2bf(mn5[3]);
    sm.tlb[32 + r0 + 0][cb] = f2bf(mn6[0]);
    sm.tlb[32 + r0 + 1][cb] = f2bf(mn6[1]);
    sm.tlb[32 + r0 + 2][cb] = f2bf(mn6[2]);
    sm.tlb[32 + r0 + 3][cb] = f2bf(mn6[3]);
    sm.tlb[48 + r0 + 0][cb] = f2bf(mn7[0]);
    sm.tlb[48 + r0 + 1][cb] = f2bf(mn7[1]);
    sm.tlb[48 + r0 + 2][cb] = f2bf(mn7[2]);
    sm.tlb[48 + r0 + 3][cb] = f2bf(mn7[3]);
    __syncthreads();
    // parts layout: [chunk][tile(64)][row 64][col 128] bf16
    unsigned short* po = parts + ((size_t)chunk * 64 + ntile) * 8192;
    #pragma unroll
    for (int p = 0; p < 4; ++p) {
      const int item = p * 256 + (int)threadIdx.x;
      const int row  = item >> 4;
      const int oct  = (item & 15) * 8;
      bf16x8 v = *(const bf16x8*)&sm.tlb[row][oct];
      *(bf16x8*)(po + (size_t)row * 128 + oct) = v;
    }
  }
}

// reduce bf16 tile-major partials: out[row][tile*128+col] = sum_c parts + bias
template<int NC>
__global__ __launch_bounds__(256) void qlin_reduce(
    const unsigned short* __restrict__ parts,
    const float* __restrict__ bias,
    float*       __restrict__ out) {
  int e = blockIdx.x * 256 + threadIdx.x;          // octet index (8 cols)
  if (e >= M_ROWS * OUT_N / 8) return;
  const int tile = e >> 10;         // 1024 octets per tile (64 rows x 16)
  const int rem  = e & 1023;
  const int row  = rem >> 4;
  const int oct  = rem & 15;
  const size_t base = ((size_t)tile * 64 + row) * 128 + oct * 8;
  constexpr size_t CS = (size_t)64 * 64 * 128;     // chunk stride (elements)
  float s[8] = {0,0,0,0,0,0,0,0};
  #pragma unroll
  for (int c = 0; c < NC; ++c) {
    bf16x8 v = *(const bf16x8*)(parts + c * CS + base);
    #pragma unroll
    for (int j = 0; j < 8; ++j)
      s[j] += __uint_as_float(((unsigned)(unsigned short)v[j]) << 16);
  }
  const int colb = tile * 128 + oct * 8;
  const f32x4* bp = (const f32x4*)(bias + colb);
  f32x4 b0 = bp[0], b1 = bp[1];
  f32x4 o0, o1;
  o0[0] = s[0] + b0[0]; o0[1] = s[1] + b0[1];
  o0[2] = s[2] + b0[2]; o0[3] = s[3] + b0[3];
  o1[0] = s[4] + b1[0]; o1[1] = s[5] + b1[1];
  o1[2] = s[6] + b1[2]; o1[3] = s[7] + b1[3];
  float* op = out + (size_t)row * OUT_N + colb;
  *(f32x4*)op = o0;
  *(f32x4*)(op + 4) = o1;
}

extern "C" void kernel_launch(void* const* d_in, const int* in_sizes, int n_in,
                              void* d_out, int out_size, void* d_ws, size_t ws_size,
                              hipStream_t stream) {
  const float* x      = (const float*)d_in[0];
  const int*   packed = (const int*)d_in[1];
  const float* absmax = (const float*)d_in[2];
  const float* bias   = (const float*)d_in[3];
  float* out = (float*)d_out;

  unsigned short* xf    = (unsigned short*)d_ws;                      // 1 MB
  unsigned short* parts = (unsigned short*)((char*)d_ws + (1 << 20)); // NC MB bf16

  qlin_prep<<<(M_ROWS * IN_K / 8 + 255) / 256, 256, 0, stream>>>(x, xf);

  const size_t chunk_bytes = (size_t)64 * 64 * 128 * sizeof(unsigned short); // 1 MB
  const size_t need16 = (size_t)(1 << 20) + 16 * chunk_bytes;
  if (ws_size >= need16) {
    qlin_main<16><<<64 * 16, 256, 0, stream>>>(packed, absmax, xf, parts);
    qlin_reduce<16><<<(M_ROWS * OUT_N / 8 + 255) / 256, 256, 0, stream>>>(parts, bias, out);
  } else {
    qlin_main<8><<<64 * 8, 256, 0, stream>>>(packed, absmax, xf, parts);
    qlin_reduce<8><<<(M_ROWS * OUT_N / 8 + 255) / 256, 256, 0, stream>>>(parts, bias, out);
  }
}